// Round 1
// baseline (239.868 us; speedup 1.0000x reference)
//
#include <hip/hip_runtime.h>
#include <math.h>

#define INV_SQRT2 0.70710678118654752440
#define PI_D 3.14159265358979323846

// ---------------------------------------------------------------------------
// Kernel A: build the fixed "J" matrices (rho_l of the rotation swapping x<->y,
// z->-z) for l=4 and l=6, in double precision, store as float into ws.
// J4 at ws[0..81), J6 at ws[96..265).
// ---------------------------------------------------------------------------
__global__ void build_J(float* __restrict__ ws) {
  const int l = (blockIdx.x == 0) ? 4 : 6;
  const int n = 2 * l + 1;
  const int off = (blockIdx.x == 0) ? 0 : 96;
  const int tid = threadIdx.x;
  __shared__ double Qr[169], Qi[169], Br[169], Bi[169], A[169], T[169], U[169];

  for (int t = tid; t < 169; t += blockDim.x) { Qr[t] = 0.0; Qi[t] = 0.0; }
  __syncthreads();

  // Q: real->complex change of basis (global (-i)^l phase cancels in Q^H X Q)
  if (tid < n) {
    int m = tid - l;
    if (m < 0) {
      Qr[tid * n + (l - m)] = INV_SQRT2;    // 1/sqrt2
      Qi[tid * n + (l + m)] = -INV_SQRT2;   // -i/sqrt2
    } else if (m == 0) {
      Qr[tid * n + l] = 1.0;
    } else {
      double sgn = (m & 1) ? -1.0 : 1.0;    // (-1)^m
      Qr[tid * n + (l + m)] = sgn * INV_SQRT2;
      Qi[tid * n + (l - m)] = sgn * INV_SQRT2;  // i*(-1)^m/sqrt2
    }
  }
  __syncthreads();

  // B = X0 * Q ; X0 = 0.5*(raising+lowering): antisymmetric tridiagonal with
  // X0[i][i+1] = 0.5*sqrt(l(l+1) - m(m+1)), m = i-l ; X0[i+1][i] = -that.
  if (tid < n * n) {
    int i = tid / n, j = tid % n;
    double br = 0.0, bi = 0.0;
    if (i + 1 < n) {
      double m = (double)(i - l);
      double v = 0.5 * sqrt((double)(l * (l + 1)) - m * (m + 1.0));
      br += v * Qr[(i + 1) * n + j];
      bi += v * Qi[(i + 1) * n + j];
    }
    if (i - 1 >= 0) {
      double m = (double)(i - 1 - l);
      double v = -0.5 * sqrt((double)(l * (l + 1)) - m * (m + 1.0));
      br += v * Qr[(i - 1) * n + j];
      bi += v * Qi[(i - 1) * n + j];
    }
    Br[tid] = br;
    Bi[tid] = bi;
  }
  __syncthreads();

  // A = (pi/sqrt2) * ( Re(Q^H B) + J_y ), scaled by 2^-8 for expm
  if (tid < n * n) {
    int i = tid / n, j = tid % n;
    double acc = 0.0;
    for (int k = 0; k < n; k++)
      acc += Qr[k * n + i] * Br[k * n + j] + Qi[k * n + i] * Bi[k * n + j];
    if (j == 2 * l - i && i != l) acc += (double)(l - i);  // J_y[i][2l-i] = l-i
    A[tid] = acc * (PI_D * INV_SQRT2) * (1.0 / 256.0);
  }
  __syncthreads();

  // expm: order-12 Taylor (Horner) + 8 squarings
  if (tid < n * n) T[tid] = (tid % (n + 1) == 0) ? 1.0 : 0.0;
  __syncthreads();
  for (int k = 12; k >= 1; k--) {
    if (tid < n * n) {
      int i = tid / n, j = tid % n;
      double acc = 0.0;
      for (int q = 0; q < n; q++) acc += A[i * n + q] * T[q * n + j];
      U[tid] = acc;
    }
    __syncthreads();
    if (tid < n * n) T[tid] = ((tid % (n + 1) == 0) ? 1.0 : 0.0) + U[tid] / (double)k;
    __syncthreads();
  }
  for (int it = 0; it < 8; it++) {
    if (tid < n * n) {
      int i = tid / n, j = tid % n;
      double acc = 0.0;
      for (int q = 0; q < n; q++) acc += T[i * n + q] * T[q * n + j];
      U[tid] = acc;
    }
    __syncthreads();
    if (tid < n * n) T[tid] = U[tid];
    __syncthreads();
  }
  if (tid < n * n) ws[off + tid] = (float)T[tid];
}

// ---------------------------------------------------------------------------
// Kernel B: main per-quaternion kernel
// ---------------------------------------------------------------------------
template <int L>
__device__ __forceinline__ void rotY(float c1, float s1, const float* v, float* o) {
  o[L] = v[L];
  float ck = c1, sk = s1;
#pragma unroll
  for (int k = 1; k <= L; k++) {
    o[L - k] = ck * v[L - k] + sk * v[L + k];
    o[L + k] = -sk * v[L - k] + ck * v[L + k];
    float cn = ck * c1 - sk * s1;
    sk = sk * c1 + ck * s1;
    ck = cn;
  }
}

template <int L>
__device__ __forceinline__ void matJ(const float* __restrict__ Jg, const float* v, float* o) {
  const int n = 2 * L + 1;
#pragma unroll
  for (int i = 0; i < n; i++) {
    float acc = 0.f;
#pragma unroll
    for (int k = 0; k < n; k++) acc = fmaf(Jg[i * n + k], v[k], acc);
    o[i] = acc;
  }
}

template <int L>
__device__ __forceinline__ void wigner_apply(const float* __restrict__ Jg,
                                             const float* __restrict__ svec,
                                             float ca, float sa, float cb, float sb,
                                             float cg, float sg, float* f) {
  const int n = 2 * L + 1;
  float t[2 * L + 1], u[2 * L + 1], sv[2 * L + 1];
#pragma unroll
  for (int k = 0; k < n; k++) sv[k] = svec[k];  // uniform -> scalar loads
  rotY<L>(cg, sg, sv, t);   // exp(gamma*Jy)
  matJ<L>(Jg, t, u);        // J
  rotY<L>(cb, sb, u, t);    // exp(beta*Jy)
  matJ<L>(Jg, t, u);        // J   => exp(beta*Jx)
  rotY<L>(ca, sa, u, f);    // exp(alpha*Jy)
}

__global__ __launch_bounds__(256) void wigner_main(
    const float4* __restrict__ quats,
    const float* __restrict__ s4,
    const float* __restrict__ s6,
    const float* __restrict__ ws,
    float* __restrict__ out,
    int B) {
  int i = blockIdx.x * 256 + threadIdx.x;
  if (i >= B) return;
  float4 q = quats[i];

  // quat -> rotation matrix (no trig: c=cos(2*acos(w))=2w^2-1, s=2w*sqrt(1-w^2))
  float w = fminf(fmaxf(q.x, -1.f), 1.f);
  float c = 2.f * w * w - 1.f;
  float s = 2.f * w * sqrtf(fmaxf(1.f - w * w, 0.f));
  float an2 = q.y * q.y + q.z * q.z + q.w * q.w;
  float inv = (an2 > 1e-24f) ? rsqrtf(an2) : 1e12f;
  float ax = q.y * inv, ay = q.z * inv, az = q.w * inv;
  float C = 1.f - c;
  float R00 = c + ax * ax * C, R01 = ax * ay * C - az * s, R02 = ax * az * C + ay * s;
  float R20 = az * ax * C - ay * s, R21 = az * ay * C + ax * s, R22 = c + az * az * C;
  float R11 = c + ay * ay * C;

  // angles from column 1 of R (cos/sin only, no arccos/atan2)
  float vx = R01, vy = R11, vz = R21;
  float n2 = vx * vx + vy * vy + vz * vz;
  float invn = (n2 > 1e-24f) ? rsqrtf(n2) : 1e12f;
  vx = fminf(fmaxf(vx * invn, -1.f), 1.f);
  vy = fminf(fmaxf(vy * invn, -1.f), 1.f);
  vz = fminf(fmaxf(vz * invn, -1.f), 1.f);
  float cb = vy;
  float sb = sqrtf(fmaxf(1.f - cb * cb, 0.f));
  float h2 = vx * vx + vz * vz;
  float ca, sa;
  if (h2 > 1e-30f) { float rh = rsqrtf(h2); ca = vz * rh; sa = vx * rh; }
  else             { ca = 1.f; sa = 0.f; }
  // gamma from M = (Y(a)X(b))^T R: M[0,j] = ca*R[0,j] - sa*R[2,j]
  float M00 = ca * R00 - sa * R20;
  float M02 = ca * R02 - sa * R22;
  float g2 = M00 * M00 + M02 * M02;
  float cg, sg;
  if (g2 > 1e-30f) { float rg = rsqrtf(g2); cg = M00 * rg; sg = M02 * rg; }
  else             { cg = 1.f; sg = 0.f; }

  float f4[9];
  wigner_apply<4>(ws, s4, ca, sa, cb, sb, cg, sg, f4);
  float* o4 = out + (size_t)i * 9;
#pragma unroll
  for (int j = 0; j < 9; j++) o4[j] = f4[j];

  float f6[13];
  wigner_apply<6>(ws + 96, s6, ca, sa, cb, sb, cg, sg, f6);
  float* o6 = out + (size_t)B * 9 + (size_t)i * 13;
#pragma unroll
  for (int j = 0; j < 13; j++) o6[j] = f6[j];
}

extern "C" void kernel_launch(void* const* d_in, const int* in_sizes, int n_in,
                              void* d_out, int out_size, void* d_ws, size_t ws_size,
                              hipStream_t stream) {
  const float4* quats = (const float4*)d_in[0];
  const float* s4 = (const float*)d_in[1];
  const float* s6 = (const float*)d_in[2];
  float* out = (float*)d_out;
  float* ws = (float*)d_ws;
  int B = in_sizes[0] / 4;

  hipLaunchKernelGGL(build_J, dim3(2), dim3(256), 0, stream, ws);
  int blocks = (B + 255) / 256;
  hipLaunchKernelGGL(wigner_main, dim3(blocks), dim3(256), 0, stream,
                     quats, s4, s6, ws, out, B);
}

// Round 2
// 198.389 us; speedup vs baseline: 1.2091x; 1.2091x over previous
//
#include <hip/hip_runtime.h>
#include <math.h>

#define INV_SQRT2 0.70710678118654752440
#define PI_D 3.14159265358979323846

// ---------------------------------------------------------------------------
// Compile-time construction of the fixed "J" matrix (rho_l of the rotation
// that conjugates exp(b*Jy) into exp(b*Jx)), replicating the reference's
// generator conventions exactly (verified on-device in R1 via runtime expm).
// ---------------------------------------------------------------------------
template <int N> struct MatF { float a[N * N]; };

constexpr double csqrt(double x) {
  if (x <= 0.0) return 0.0;
  double g = x > 1.0 ? x : 1.0;
  for (int i = 0; i < 40; ++i) g = 0.5 * (g + x / g);
  return g;
}

template <int L>
constexpr MatF<2 * L + 1> makeJ() {
  constexpr int n = 2 * L + 1;
  // Q: real->complex change of basis (global (-i)^l phase cancels in Q^H X Q)
  double Qr[n * n] = {}, Qi[n * n] = {};
  for (int r = 0; r < n; ++r) {
    int m = r - L;
    if (m < 0) {
      Qr[r * n + (L - m)] = INV_SQRT2;
      Qi[r * n + (L + m)] = -INV_SQRT2;
    } else if (m == 0) {
      Qr[r * n + L] = 1.0;
    } else {
      double sgn = (m & 1) ? -1.0 : 1.0;
      Qr[r * n + (L + m)] = sgn * INV_SQRT2;
      Qi[r * n + (L - m)] = sgn * INV_SQRT2;
    }
  }
  // X0 superdiagonal values: X0[i][i+1] = c[i], X0[i][i-1] = -c[i-1]
  double c[n] = {};
  for (int i = 0; i + 1 < n; ++i) {
    double m = (double)(i - L);
    c[i] = 0.5 * csqrt((double)(L * (L + 1)) - m * (m + 1.0));
  }
  // B = X0 * Q
  double Br[n * n] = {}, Bi[n * n] = {};
  for (int i = 0; i < n; ++i)
    for (int j = 0; j < n; ++j) {
      double br = 0, bi = 0;
      if (i + 1 < n) { br += c[i] * Qr[(i + 1) * n + j]; bi += c[i] * Qi[(i + 1) * n + j]; }
      if (i >= 1)    { br -= c[i - 1] * Qr[(i - 1) * n + j]; bi -= c[i - 1] * Qi[(i - 1) * n + j]; }
      Br[i * n + j] = br;
      Bi[i * n + j] = bi;
    }
  // A = (pi/sqrt2) * (Re(Q^H B) + Jy_real), scaled 2^-6 for expm
  double A[n * n] = {};
  for (int i = 0; i < n; ++i)
    for (int j = 0; j < n; ++j) {
      double acc = 0;
      for (int k = 0; k < n; ++k)
        acc += Qr[k * n + i] * Br[k * n + j] + Qi[k * n + i] * Bi[k * n + j];
      if (j == 2 * L - i && i != L) acc += (double)(L - i);  // Jy[i][2l-i] = l-i
      A[i * n + j] = acc * (PI_D * INV_SQRT2) * (1.0 / 64.0);
    }
  // expm: order-10 Taylor (Horner) + 6 squarings (||A|| <= 6*pi/64 ~ 0.29)
  double T[n * n] = {}, U[n * n] = {};
  for (int i = 0; i < n; ++i) T[i * n + i] = 1.0;
  for (int k = 10; k >= 1; --k) {
    for (int i = 0; i < n; ++i)
      for (int j = 0; j < n; ++j) {
        double acc = 0;
        for (int q = 0; q < n; ++q) acc += A[i * n + q] * T[q * n + j];
        U[i * n + j] = acc;
      }
    double inv = 1.0 / (double)k;
    for (int i = 0; i < n; ++i)
      for (int j = 0; j < n; ++j)
        T[i * n + j] = ((i == j) ? 1.0 : 0.0) + U[i * n + j] * inv;
  }
  for (int s = 0; s < 6; ++s) {
    for (int i = 0; i < n; ++i)
      for (int j = 0; j < n; ++j) {
        double acc = 0;
        for (int q = 0; q < n; ++q) acc += T[i * n + q] * T[q * n + j];
        U[i * n + j] = acc;
      }
    for (int t = 0; t < n * n; ++t) T[t] = U[t];
  }
  MatF<n> R = {};
  for (int t = 0; t < n * n; ++t) {
    double v = T[t];
    if (v < 1e-9 && v > -1e-9) v = 0.0;  // snap exact zeros -> compiler drops FMA
    R.a[t] = (float)v;
  }
  return R;
}

__device__ constexpr MatF<9>  J4 = makeJ<4>();
__device__ constexpr MatF<13> J6 = makeJ<6>();

// ---------------------------------------------------------------------------
// Per-quaternion kernel
// ---------------------------------------------------------------------------
template <int L>
__device__ __forceinline__ void rotY(float c1, float s1, const float* v, float* o) {
  o[L] = v[L];
  float ck = c1, sk = s1;
#pragma unroll
  for (int k = 1; k <= L; k++) {
    o[L - k] = ck * v[L - k] + sk * v[L + k];
    o[L + k] = -sk * v[L - k] + ck * v[L + k];
    float cn = ck * c1 - sk * s1;
    sk = sk * c1 + ck * s1;
    ck = cn;
  }
}

template <int L>
__device__ __forceinline__ void matJ(const float* __restrict__ Jg, const float* v, float* o) {
  constexpr int n = 2 * L + 1;
#pragma unroll
  for (int i = 0; i < n; i++) {
    float acc = 0.f;
#pragma unroll
    for (int k = 0; k < n; k++) {
      if (Jg[i * n + k] != 0.0f)  // compile-time constant -> folded, zeros dropped
        acc = fmaf(Jg[i * n + k], v[k], acc);
    }
    o[i] = acc;
  }
}

template <int L>
__device__ __forceinline__ void wigner_apply(const float* __restrict__ Jg,
                                             const float* __restrict__ svec,
                                             float ca, float sa, float cb, float sb,
                                             float cg, float sg, float* f) {
  constexpr int n = 2 * L + 1;
  float t[n], u[n], sv[n];
#pragma unroll
  for (int k = 0; k < n; k++) sv[k] = svec[k];  // uniform -> scalar loads
  rotY<L>(cg, sg, sv, t);   // exp(gamma*Jy)
  matJ<L>(Jg, t, u);        // J
  rotY<L>(cb, sb, u, t);    // exp(beta*Jy)
  matJ<L>(Jg, t, u);        // J   => exp(beta*Jx)
  rotY<L>(ca, sa, u, f);    // exp(alpha*Jy)
}

__global__ __launch_bounds__(256) void wigner_main(
    const float4* __restrict__ quats,
    const float* __restrict__ s4,
    const float* __restrict__ s6,
    float* __restrict__ out,
    int B) {
  __shared__ float lds[2304 + 3328];  // 256*9 + 256*13 floats = 22528 B
  const int t = threadIdx.x;
  const int b = blockIdx.x;
  const int i = b * 256 + t;
  const int idx = (i < B) ? i : (B - 1);
  float4 q = quats[idx];

  // quat -> rotation matrix (no trig: c=cos(2*acos(w))=2w^2-1, s=2w*sqrt(1-w^2))
  float w = fminf(fmaxf(q.x, -1.f), 1.f);
  float c = 2.f * w * w - 1.f;
  float s = 2.f * w * sqrtf(fmaxf(1.f - w * w, 0.f));
  float an2 = q.y * q.y + q.z * q.z + q.w * q.w;
  float inv = (an2 > 1e-24f) ? rsqrtf(an2) : 1e12f;
  float ax = q.y * inv, ay = q.z * inv, az = q.w * inv;
  float C = 1.f - c;
  float R00 = c + ax * ax * C, R01 = ax * ay * C - az * s, R02 = ax * az * C + ay * s;
  float R20 = az * ax * C - ay * s, R21 = az * ay * C + ax * s, R22 = c + az * az * C;
  float R11 = c + ay * ay * C;

  // Euler cos/sin straight from matrix entries (no arccos/atan2)
  float vx = R01, vy = R11, vz = R21;
  float n2 = vx * vx + vy * vy + vz * vz;
  float invn = (n2 > 1e-24f) ? rsqrtf(n2) : 1e12f;
  vx = fminf(fmaxf(vx * invn, -1.f), 1.f);
  vy = fminf(fmaxf(vy * invn, -1.f), 1.f);
  vz = fminf(fmaxf(vz * invn, -1.f), 1.f);
  float cb = vy;
  float sb = sqrtf(fmaxf(1.f - cb * cb, 0.f));
  float h2 = vx * vx + vz * vz;
  float ca, sa;
  if (h2 > 1e-30f) { float rh = rsqrtf(h2); ca = vz * rh; sa = vx * rh; }
  else             { ca = 1.f; sa = 0.f; }
  float M00 = ca * R00 - sa * R20;
  float M02 = ca * R02 - sa * R22;
  float g2 = M00 * M00 + M02 * M02;
  float cg, sg;
  if (g2 > 1e-30f) { float rg = rsqrtf(g2); cg = M00 * rg; sg = M02 * rg; }
  else             { cg = 1.f; sg = 0.f; }

  float f4[9];
  wigner_apply<4>(J4.a, s4, ca, sa, cb, sb, cg, sg, f4);
  float f6[13];
  wigner_apply<6>(J6.a, s6, ca, sa, cb, sb, cg, sg, f6);

  const bool full = (b + 1) * 256 <= B;  // block-uniform
  if (full) {
    // stage in LDS, then fully-coalesced dword stores
#pragma unroll
    for (int j = 0; j < 9; j++) lds[t * 9 + j] = f4[j];          // stride 9: 2-way, free
#pragma unroll
    for (int j = 0; j < 13; j++) lds[2304 + t * 13 + j] = f6[j]; // stride 13: 2-way, free
    __syncthreads();
    float* o4 = out + (size_t)b * 2304;
#pragma unroll
    for (int j = 0; j < 9; j++) o4[j * 256 + t] = lds[j * 256 + t];
    float* o6 = out + (size_t)B * 9 + (size_t)b * 3328;
#pragma unroll
    for (int j = 0; j < 13; j++) o6[j * 256 + t] = lds[2304 + j * 256 + t];
  } else if (i < B) {
    float* o4 = out + (size_t)i * 9;
#pragma unroll
    for (int j = 0; j < 9; j++) o4[j] = f4[j];
    float* o6 = out + (size_t)B * 9 + (size_t)i * 13;
#pragma unroll
    for (int j = 0; j < 13; j++) o6[j] = f6[j];
  }
}

extern "C" void kernel_launch(void* const* d_in, const int* in_sizes, int n_in,
                              void* d_out, int out_size, void* d_ws, size_t ws_size,
                              hipStream_t stream) {
  const float4* quats = (const float4*)d_in[0];
  const float* s4 = (const float*)d_in[1];
  const float* s6 = (const float*)d_in[2];
  float* out = (float*)d_out;
  int B = in_sizes[0] / 4;
  int blocks = (B + 255) / 256;
  hipLaunchKernelGGL(wigner_main, dim3(blocks), dim3(256), 0, stream,
                     quats, s4, s6, out, B);
}

// Round 3
// 195.446 us; speedup vs baseline: 1.2273x; 1.0151x over previous
//
#include <hip/hip_runtime.h>
#include <math.h>

#define INV_SQRT2 0.70710678118654752440
#define PI_D 3.14159265358979323846

// ---------------------------------------------------------------------------
// Compile-time construction of the fixed "J" matrix (rho_l of the rotation
// that conjugates exp(b*Jy) into exp(b*Jx)), replicating the reference's
// generator conventions exactly (verified on-device in R1 via runtime expm;
// constexpr version matched with absmax 0.0156 in R2).
// ---------------------------------------------------------------------------
template <int N> struct MatF { float a[N * N]; };

constexpr double csqrt(double x) {
  if (x <= 0.0) return 0.0;
  double g = x > 1.0 ? x : 1.0;
  for (int i = 0; i < 40; ++i) g = 0.5 * (g + x / g);
  return g;
}

template <int L>
constexpr MatF<2 * L + 1> makeJ() {
  constexpr int n = 2 * L + 1;
  double Qr[n * n] = {}, Qi[n * n] = {};
  for (int r = 0; r < n; ++r) {
    int m = r - L;
    if (m < 0) {
      Qr[r * n + (L - m)] = INV_SQRT2;
      Qi[r * n + (L + m)] = -INV_SQRT2;
    } else if (m == 0) {
      Qr[r * n + L] = 1.0;
    } else {
      double sgn = (m & 1) ? -1.0 : 1.0;
      Qr[r * n + (L + m)] = sgn * INV_SQRT2;
      Qi[r * n + (L - m)] = sgn * INV_SQRT2;
    }
  }
  double c[n] = {};
  for (int i = 0; i + 1 < n; ++i) {
    double m = (double)(i - L);
    c[i] = 0.5 * csqrt((double)(L * (L + 1)) - m * (m + 1.0));
  }
  double Br[n * n] = {}, Bi[n * n] = {};
  for (int i = 0; i < n; ++i)
    for (int j = 0; j < n; ++j) {
      double br = 0, bi = 0;
      if (i + 1 < n) { br += c[i] * Qr[(i + 1) * n + j]; bi += c[i] * Qi[(i + 1) * n + j]; }
      if (i >= 1)    { br -= c[i - 1] * Qr[(i - 1) * n + j]; bi -= c[i - 1] * Qi[(i - 1) * n + j]; }
      Br[i * n + j] = br;
      Bi[i * n + j] = bi;
    }
  double A[n * n] = {};
  for (int i = 0; i < n; ++i)
    for (int j = 0; j < n; ++j) {
      double acc = 0;
      for (int k = 0; k < n; ++k)
        acc += Qr[k * n + i] * Br[k * n + j] + Qi[k * n + i] * Bi[k * n + j];
      if (j == 2 * L - i && i != L) acc += (double)(L - i);  // Jy[i][2l-i] = l-i
      A[i * n + j] = acc * (PI_D * INV_SQRT2) * (1.0 / 64.0);
    }
  double T[n * n] = {}, U[n * n] = {};
  for (int i = 0; i < n; ++i) T[i * n + i] = 1.0;
  for (int k = 10; k >= 1; --k) {
    for (int i = 0; i < n; ++i)
      for (int j = 0; j < n; ++j) {
        double acc = 0;
        for (int q = 0; q < n; ++q) acc += A[i * n + q] * T[q * n + j];
        U[i * n + j] = acc;
      }
    double inv = 1.0 / (double)k;
    for (int i = 0; i < n; ++i)
      for (int j = 0; j < n; ++j)
        T[i * n + j] = ((i == j) ? 1.0 : 0.0) + U[i * n + j] * inv;
  }
  for (int s = 0; s < 6; ++s) {
    for (int i = 0; i < n; ++i)
      for (int j = 0; j < n; ++j) {
        double acc = 0;
        for (int q = 0; q < n; ++q) acc += T[i * n + q] * T[q * n + j];
        U[i * n + j] = acc;
      }
    for (int t = 0; t < n * n; ++t) T[t] = U[t];
  }
  MatF<n> R = {};
  for (int t = 0; t < n * n; ++t) {
    double v = T[t];
    if (v < 1e-9 && v > -1e-9) v = 0.0;  // snap exact zeros -> if-constexpr drops FMA
    R.a[t] = (float)v;
  }
  return R;
}

template <int L> struct JMat { static constexpr MatF<2 * L + 1> M = makeJ<L>(); };

// matJ with GUARANTEED compile-time weights: each J entry is a constexpr float
// (literal operand), zero entries removed by `if constexpr` — no memory loads,
// no runtime tests, regardless of optimizer behavior.
template <int L, int I, int K>
__device__ __forceinline__ float matJ_dot(const float* v) {
  if constexpr (K < 0) {
    return 0.f;
  } else {
    float acc = matJ_dot<L, I, K - 1>(v);
    constexpr float w = JMat<L>::M.a[I * (2 * L + 1) + K];
    if constexpr (w != 0.0f) acc = fmaf(w, v[K], acc);
    return acc;
  }
}

template <int L, int I>
__device__ __forceinline__ void matJ_rows(const float* v, float* o) {
  if constexpr (I >= 0) {
    matJ_rows<L, I - 1>(v, o);
    o[I] = matJ_dot<L, I, 2 * L>(v);
  }
}

template <int L>
__device__ __forceinline__ void matJ(const float* v, float* o) {
  matJ_rows<L, 2 * L>(v, o);
}

// ---------------------------------------------------------------------------
// Per-quaternion kernel
// ---------------------------------------------------------------------------
template <int L>
__device__ __forceinline__ void rotY(float c1, float s1, const float* v, float* o) {
  o[L] = v[L];
  float ck = c1, sk = s1;
#pragma unroll
  for (int k = 1; k <= L; k++) {
    o[L - k] = ck * v[L - k] + sk * v[L + k];
    o[L + k] = -sk * v[L - k] + ck * v[L + k];
    float cn = ck * c1 - sk * s1;
    sk = sk * c1 + ck * s1;
    ck = cn;
  }
}

template <int L>
__device__ __forceinline__ void wigner_apply(const float* __restrict__ svec,
                                             float ca, float sa, float cb, float sb,
                                             float cg, float sg, float* f) {
  constexpr int n = 2 * L + 1;
  float t[n], u[n], sv[n];
#pragma unroll
  for (int k = 0; k < n; k++) sv[k] = svec[k];  // uniform -> scalar loads
  rotY<L>(cg, sg, sv, t);   // exp(gamma*Jy)
  matJ<L>(t, u);            // J
  rotY<L>(cb, sb, u, t);    // exp(beta*Jy)
  matJ<L>(t, u);            // J   => exp(beta*Jx)
  rotY<L>(ca, sa, u, f);    // exp(alpha*Jy)  (f may be an LDS pointer)
}

__global__ __launch_bounds__(256) void wigner_main(
    const float4* __restrict__ quats,
    const float* __restrict__ s4,
    const float* __restrict__ s6,
    float* __restrict__ out,
    int B) {
  __shared__ float lds[2304 + 3328];  // 256*9 + 256*13 floats = 22528 B
  const int t = threadIdx.x;
  const int b = blockIdx.x;
  const int i = b * 256 + t;
  const int idx = (i < B) ? i : (B - 1);
  float4 q = quats[idx];

  // quat -> rotation matrix (no trig: c=cos(2*acos(w))=2w^2-1, s=2w*sqrt(1-w^2))
  float w = fminf(fmaxf(q.x, -1.f), 1.f);
  float c = 2.f * w * w - 1.f;
  float s = 2.f * w * sqrtf(fmaxf(1.f - w * w, 0.f));
  float an2 = q.y * q.y + q.z * q.z + q.w * q.w;
  float inv = (an2 > 1e-24f) ? rsqrtf(an2) : 1e12f;
  float ax = q.y * inv, ay = q.z * inv, az = q.w * inv;
  float C = 1.f - c;
  float R00 = c + ax * ax * C, R01 = ax * ay * C - az * s, R02 = ax * az * C + ay * s;
  float R20 = az * ax * C - ay * s, R21 = az * ay * C + ax * s, R22 = c + az * az * C;
  float R11 = c + ay * ay * C;

  // Euler cos/sin straight from matrix entries (no arccos/atan2)
  float vx = R01, vy = R11, vz = R21;
  float n2 = vx * vx + vy * vy + vz * vz;
  float invn = (n2 > 1e-24f) ? rsqrtf(n2) : 1e12f;
  vx = fminf(fmaxf(vx * invn, -1.f), 1.f);
  vy = fminf(fmaxf(vy * invn, -1.f), 1.f);
  vz = fminf(fmaxf(vz * invn, -1.f), 1.f);
  float cb = vy;
  float sb = sqrtf(fmaxf(1.f - cb * cb, 0.f));
  float h2 = vx * vx + vz * vz;
  float ca, sa;
  if (h2 > 1e-30f) { float rh = rsqrtf(h2); ca = vz * rh; sa = vx * rh; }
  else             { ca = 1.f; sa = 0.f; }
  float M00 = ca * R00 - sa * R20;
  float M02 = ca * R02 - sa * R22;
  float g2 = M00 * M00 + M02 * M02;
  float cg, sg;
  if (g2 > 1e-30f) { float rg = rsqrtf(g2); cg = M00 * rg; sg = M02 * rg; }
  else             { cg = 1.f; sg = 0.f; }

  // Compute straight into LDS (short register live ranges)
  wigner_apply<4>(s4, ca, sa, cb, sb, cg, sg, &lds[t * 9]);          // stride 9: 2-way, free
  wigner_apply<6>(s6, ca, sa, cb, sb, cg, sg, &lds[2304 + t * 13]);  // stride 13: 2-way, free
  __syncthreads();

  const bool full = (b + 1) * 256 <= B;  // block-uniform
  if (full && (B & 3) == 0) {
    // fully-coalesced float4 stores: 3 + 4 dwordx4 per thread
    const float4* l4 = (const float4*)lds;
    float4* o4 = (float4*)(out + (size_t)b * 2304);
#pragma unroll
    for (int v = t; v < 576; v += 256) o4[v] = l4[v];
    const float4* l6 = (const float4*)(lds + 2304);
    float4* o6 = (float4*)(out + (size_t)B * 9 + (size_t)b * 3328);
#pragma unroll
    for (int v = t; v < 832; v += 256) o6[v] = l6[v];
  } else if (i < B) {
    float* o4 = out + (size_t)i * 9;
#pragma unroll
    for (int j = 0; j < 9; j++) o4[j] = lds[t * 9 + j];
    float* o6 = out + (size_t)B * 9 + (size_t)i * 13;
#pragma unroll
    for (int j = 0; j < 13; j++) o6[j] = lds[2304 + t * 13 + j];
  }
}

extern "C" void kernel_launch(void* const* d_in, const int* in_sizes, int n_in,
                              void* d_out, int out_size, void* d_ws, size_t ws_size,
                              hipStream_t stream) {
  const float4* quats = (const float4*)d_in[0];
  const float* s4 = (const float*)d_in[1];
  const float* s6 = (const float*)d_in[2];
  float* out = (float*)d_out;
  int B = in_sizes[0] / 4;
  int blocks = (B + 255) / 256;
  hipLaunchKernelGGL(wigner_main, dim3(blocks), dim3(256), 0, stream,
                     quats, s4, s6, out, B);
}